// Round 1
// baseline (5310.369 us; speedup 1.0000x reference)
//
#include <hip/hip_runtime.h>
#include <math.h>

#define B_N 256
#define V_N 6890
#define J_N 24
#define KPF 207
#define KE  218
#define NCOL (V_N*3)   // 20670

__device__ __constant__ int c_par[24] = {-1,0,0,0,1,2,3,4,5,6,7,8,9,9,9,12,13,14,16,17,18,19,20,21};

// ws layout (floats)
#define WS_PF   0
#define WS_A    (WS_PF + B_N*KE)                 // 55808
#define WS_EXT  (WS_A + B_N*J_N*12)              // 129536
#define WS_JS   (WS_EXT + 11*NCOL)               // 356906
#define WS_JT0  (WS_JS + J_N*30)                 // 357626
#define WS_PART (WS_JT0 + J_N*3)                 // 357698  (96*33 = 3168)

// ---------------- stage 0a: partial joint-regressor contraction ----------------
// JS[j,k,l] = sum_v Jreg[j,v]*shapedirs[v,k,l];  Jt0[j,k] = sum_v Jreg[j,v]*vt[v,k]
__global__ __launch_bounds__(256) void k_jreg(const float* __restrict__ Jreg,
        const float* __restrict__ vt, const float* __restrict__ sd,
        float* __restrict__ part)
{
    int j = blockIdx.x;
    int c = blockIdx.y;
    int tid = threadIdx.x;
    int v0 = c * 1723;
    int v1 = v0 + 1723; if (v1 > V_N) v1 = V_N;

    float acc[33];
    #pragma unroll
    for (int i = 0; i < 33; ++i) acc[i] = 0.f;

    for (int v = v0 + tid; v < v1; v += 256) {
        float r = Jreg[j*V_N + v];
        const float* s = sd + v*30;
        #pragma unroll
        for (int i = 0; i < 30; ++i) acc[i] += r * s[i];
        #pragma unroll
        for (int k = 0; k < 3; ++k) acc[30+k] += r * vt[v*3+k];
    }
    #pragma unroll
    for (int i = 0; i < 33; ++i) {
        #pragma unroll
        for (int off = 32; off > 0; off >>= 1)
            acc[i] += __shfl_down(acc[i], off, 64);
    }
    __shared__ float red[4][33];
    int wave = tid >> 6, lane = tid & 63;
    if (lane == 0) {
        #pragma unroll
        for (int i = 0; i < 33; ++i) red[wave][i] = acc[i];
    }
    __syncthreads();
    if (tid < 33) {
        float s = red[0][tid] + red[1][tid] + red[2][tid] + red[3][tid];
        part[(j*4 + c)*33 + tid] = s;
    }
}

__global__ __launch_bounds__(64) void k_jred(const float* __restrict__ part,
        float* __restrict__ JS, float* __restrict__ Jt0)
{
    int j = blockIdx.x;
    int tid = threadIdx.x;
    if (tid < 33) {
        float s = 0.f;
        for (int c = 0; c < 4; ++c) s += part[(j*4 + c)*33 + tid];
        if (tid < 30) JS[j*30 + tid] = s;
        else          Jt0[j*3 + (tid - 30)] = s;
    }
}

// ---------------- stage 0b: build extended "posedirs" rows 207..217 ----------------
// EXT[l][v*3+k] = shapedirs[v,k,l]  (l<10);  EXT[10][v*3+k] = v_template[v,k]
__global__ __launch_bounds__(256) void k_ext(const float* __restrict__ sd,
        const float* __restrict__ vt, float* __restrict__ EXT)
{
    int idx = blockIdx.x*256 + threadIdx.x;
    if (idx >= NCOL) return;
    int v = idx / 3, k = idx - v*3;
    #pragma unroll
    for (int l = 0; l < 10; ++l) EXT[l*NCOL + idx] = sd[v*30 + k*10 + l];
    EXT[10*NCOL + idx] = vt[idx];
}

// ---------------- stage 1: per-batch Rodrigues + kinematic chain ----------------
__global__ __launch_bounds__(64) void k_batch(const float* __restrict__ pose,
        const float* __restrict__ betas, const float* __restrict__ JS,
        const float* __restrict__ Jt0, float* __restrict__ PF,
        float* __restrict__ A, float* __restrict__ outJ)
{
    int b = blockIdx.x;
    int lane = threadIdx.x;
    __shared__ float sR[24][9];
    __shared__ float sJ[24][3];
    __shared__ float sG[24][12];

    if (lane < 24) {
        float R[9];
        if (lane < 22) {
            float p0 = pose[b*72 + lane*3 + 0];
            float p1 = pose[b*72 + lane*3 + 1];
            float p2 = pose[b*72 + lane*3 + 2];
            float a0 = p0 + 1e-8f, a1 = p1 + 1e-8f, a2 = p2 + 1e-8f;
            float angle = sqrtf(a0*a0 + a1*a1 + a2*a2);
            float inv = 1.f / angle;
            float rx = p0*inv, ry = p1*inv, rz = p2*inv;
            float cc = cosf(angle), ss = sinf(angle), ic = 1.f - cc;
            R[0] = 1.f - ic*(ry*ry + rz*rz);
            R[1] = -ss*rz + ic*rx*ry;
            R[2] =  ss*ry + ic*rx*rz;
            R[3] =  ss*rz + ic*rx*ry;
            R[4] = 1.f - ic*(rx*rx + rz*rz);
            R[5] = -ss*rx + ic*ry*rz;
            R[6] = -ss*ry + ic*rx*rz;
            R[7] =  ss*rx + ic*ry*rz;
            R[8] = 1.f - ic*(rx*rx + ry*ry);
        } else {
            R[0]=1.f;R[1]=0.f;R[2]=0.f;R[3]=0.f;R[4]=1.f;R[5]=0.f;R[6]=0.f;R[7]=0.f;R[8]=1.f;
        }
        #pragma unroll
        for (int e = 0; e < 9; ++e) sR[lane][e] = R[e];
    }
    __syncthreads();
    for (int idx = lane; idx < 72; idx += 64) {
        float s = Jt0[idx];
        #pragma unroll
        for (int l = 0; l < 10; ++l) s += betas[b*10+l] * JS[idx*10 + l];
        sJ[idx/3][idx%3] = s;
    }
    __syncthreads();
    // PF rows 0..206 = pose_feature; 207..216 = betas; 217 = 1.0
    for (int idx = lane; idx < KPF; idx += 64) {
        int jj = 1 + idx/9, e = idx - (idx/9)*9;
        float id = (e==0 || e==4 || e==8) ? 1.f : 0.f;
        PF[b*KE + idx] = sR[jj][e] - id;
    }
    if (lane < 10) PF[b*KE + KPF + lane] = betas[b*10 + lane];
    if (lane == 0) PF[b*KE + 217] = 1.f;

    if (lane == 0) {
        #pragma unroll
        for (int r = 0; r < 3; ++r) {
            sG[0][r*4+0] = sR[0][r*3+0];
            sG[0][r*4+1] = sR[0][r*3+1];
            sG[0][r*4+2] = sR[0][r*3+2];
            sG[0][r*4+3] = sJ[0][r];
        }
        for (int i = 1; i < 24; ++i) {
            int p = c_par[i];
            float rel0 = sJ[i][0]-sJ[p][0], rel1 = sJ[i][1]-sJ[p][1], rel2 = sJ[i][2]-sJ[p][2];
            for (int r = 0; r < 3; ++r) {
                float g0 = sG[p][r*4+0], g1 = sG[p][r*4+1], g2 = sG[p][r*4+2], g3 = sG[p][r*4+3];
                sG[i][r*4+0] = g0*sR[i][0] + g1*sR[i][3] + g2*sR[i][6];
                sG[i][r*4+1] = g0*sR[i][1] + g1*sR[i][4] + g2*sR[i][7];
                sG[i][r*4+2] = g0*sR[i][2] + g1*sR[i][5] + g2*sR[i][8];
                sG[i][r*4+3] = g0*rel0 + g1*rel1 + g2*rel2 + g3;
            }
        }
    }
    __syncthreads();
    if (lane < 24) {
        int i = lane;
        #pragma unroll
        for (int r = 0; r < 3; ++r) {
            float g0 = sG[i][r*4+0], g1 = sG[i][r*4+1], g2 = sG[i][r*4+2], g3 = sG[i][r*4+3];
            outJ[b*72 + i*3 + r] = g3;
            float t = g3 - (g0*sJ[i][0] + g1*sJ[i][1] + g2*sJ[i][2]);
            A[(b*24+i)*12 + r*4+0] = g0;
            A[(b*24+i)*12 + r*4+1] = g1;
            A[(b*24+i)*12 + r*4+2] = g2;
            A[(b*24+i)*12 + r*4+3] = t;
        }
    }
}

// ---------------- stage 2: fused (v_posed GEMM + skinning) ----------------
// block = 256 thr = 4 waves. Block tile: 64 verts x 16 batches.
// lane: b_l = lane>>4 (4 batches/wave), v_l = lane&15; each thread: 4 verts x 1 batch.
__global__ __launch_bounds__(256) void k_verts(
        const float* __restrict__ posedirs, const float* __restrict__ EXT,
        const float* __restrict__ PF, const float* __restrict__ A,
        const float* __restrict__ W, float* __restrict__ out)
{
    constexpr int KT = 28;
    __shared__ __align__(16) float sPFt[KE][16];       // 13952 B
    __shared__ __align__(16) float sW[64][25];         //  6400 B
    __shared__ __align__(16) float sPD[KT*64*4];       // 28672 B (reused as sA in epilogue)
    float* sA = sPD;                                    // 16*296 = 4736 floats needed

    int tid  = threadIdx.x;
    int wave = tid >> 6, lane = tid & 63;
    int v_l  = lane & 15, b_l = lane >> 4;
    int v0 = blockIdx.x * 64;
    int b0 = blockIdx.y * 16;
    int bb = wave*4 + b_l;        // block-local batch index 0..15
    int b  = b0 + bb;

    for (int idx = tid; idx < 16*KE; idx += 256) {
        int bl = idx / KE, r = idx - bl*KE;
        sPFt[r][bl] = PF[(b0+bl)*KE + r];
    }
    for (int idx = tid; idx < 64*24; idx += 256) {
        int vv = idx / 24, j = idx - vv*24;
        int vg = v0 + vv;
        sW[vv][j] = (vg < V_N) ? W[vg*24 + j] : 0.f;
    }
    __syncthreads();

    float acc[4][3];
    #pragma unroll
    for (int t = 0; t < 4; ++t) { acc[t][0]=0.f; acc[t][1]=0.f; acc[t][2]=0.f; }

    for (int rt = 0; rt < KE; rt += KT) {
        int rows = KE - rt; if (rows > KT) rows = KT;
        for (int idx = tid; idx < rows*192; idx += 256) {
            int rr = idx / 192, c = idx - rr*192;
            int r = rt + rr;
            int col = v0*3 + c; if (col >= NCOL) col = NCOL - 1;
            const float* src = (r < KPF) ? (posedirs + (size_t)r*NCOL)
                                         : (EXT + (size_t)(r-KPF)*NCOL);
            int vv = c / 3;
            sPD[(rr*64 + vv)*4 + (c - vv*3)] = src[col];
        }
        __syncthreads();
        for (int rr = 0; rr < rows; ++rr) {
            float pf = sPFt[rt+rr][bb];
            #pragma unroll
            for (int t = 0; t < 4; ++t) {
                const float4 c4 = *reinterpret_cast<const float4*>(&sPD[(rr*64 + t*16 + v_l)*4]);
                acc[t][0] += pf*c4.x;
                acc[t][1] += pf*c4.y;
                acc[t][2] += pf*c4.z;
            }
        }
        __syncthreads();
    }

    // epilogue: stage A (16 batches x 24 joints x 12) into reused LDS, stride 296
    for (int idx = tid; idx < 16*288; idx += 256) {
        int bl = idx / 288, e = idx - bl*288;
        sA[bl*296 + e] = A[(size_t)(b0+bl)*288 + e];
    }
    __syncthreads();

    float T[4][12];
    #pragma unroll
    for (int t = 0; t < 4; ++t)
        #pragma unroll
        for (int e = 0; e < 12; ++e) T[t][e] = 0.f;

    const float* Ab = sA + bb*296;
    for (int j = 0; j < 24; ++j) {
        float4 a0 = *reinterpret_cast<const float4*>(Ab + j*12 + 0);
        float4 a1 = *reinterpret_cast<const float4*>(Ab + j*12 + 4);
        float4 a2 = *reinterpret_cast<const float4*>(Ab + j*12 + 8);
        #pragma unroll
        for (int t = 0; t < 4; ++t) {
            float wv = sW[t*16 + v_l][j];
            T[t][0] += wv*a0.x; T[t][1] += wv*a0.y; T[t][2]  += wv*a0.z; T[t][3]  += wv*a0.w;
            T[t][4] += wv*a1.x; T[t][5] += wv*a1.y; T[t][6]  += wv*a1.z; T[t][7]  += wv*a1.w;
            T[t][8] += wv*a2.x; T[t][9] += wv*a2.y; T[t][10] += wv*a2.z; T[t][11] += wv*a2.w;
        }
    }
    #pragma unroll
    for (int t = 0; t < 4; ++t) {
        int v = v0 + t*16 + v_l;
        if (v < V_N) {
            float x = acc[t][0], y = acc[t][1], z = acc[t][2];
            size_t o = (size_t)b*NCOL + (size_t)v*3;
            out[o+0] = T[t][0]*x + T[t][1]*y + T[t][2]*z  + T[t][3];
            out[o+1] = T[t][4]*x + T[t][5]*y + T[t][6]*z  + T[t][7];
            out[o+2] = T[t][8]*x + T[t][9]*y + T[t][10]*z + T[t][11];
        }
    }
}

extern "C" void kernel_launch(void* const* d_in, const int* in_sizes, int n_in,
                              void* d_out, int out_size, void* d_ws, size_t ws_size,
                              hipStream_t stream)
{
    const float* betas      = (const float*)d_in[0];
    const float* pose       = (const float*)d_in[1];
    const float* v_template = (const float*)d_in[2];
    const float* shapedirs  = (const float*)d_in[3];
    const float* posedirs   = (const float*)d_in[4];
    const float* Jreg       = (const float*)d_in[5];
    const float* lbs        = (const float*)d_in[6];

    float* ws   = (float*)d_ws;
    float* PF   = ws + WS_PF;
    float* A    = ws + WS_A;
    float* EXT  = ws + WS_EXT;
    float* JS   = ws + WS_JS;
    float* Jt0  = ws + WS_JT0;
    float* part = ws + WS_PART;

    float* verts = (float*)d_out;
    float* outJ  = verts + (size_t)B_N*V_N*3;

    hipLaunchKernelGGL(k_jreg, dim3(24,4), dim3(256), 0, stream, Jreg, v_template, shapedirs, part);
    hipLaunchKernelGGL(k_ext, dim3((NCOL+255)/256), dim3(256), 0, stream, shapedirs, v_template, EXT);
    hipLaunchKernelGGL(k_jred, dim3(24), dim3(64), 0, stream, part, JS, Jt0);
    hipLaunchKernelGGL(k_batch, dim3(256), dim3(64), 0, stream, pose, betas, JS, Jt0, PF, A, outJ);
    hipLaunchKernelGGL(k_verts, dim3((V_N+63)/64, 16), dim3(256), 0, stream, posedirs, EXT, PF, A, lbs, verts);
}